// Round 4
// baseline (116.527 us; speedup 1.0000x reference)
//
#include <hip/hip_runtime.h>
#include <stdint.h>

typedef __bf16 bf16_t;
typedef bf16_t bf16x8 __attribute__((ext_vector_type(8)));
typedef float floatx4 __attribute__((ext_vector_type(4)));

#define HW 56
#define NTOK 6272   // 2*56*56

__device__ __forceinline__ uint16_t f2bf(float f){
  union { float f; uint32_t i; } c; c.f = f;
  uint32_t r = (c.i + 0x7FFFu + ((c.i >> 16) & 1u)) >> 16;
  return (uint16_t)r;
}
__device__ __forceinline__ float bflo(uint32_t u){
  union { uint32_t i; float f; } c; c.i = u << 16; return c.f;
}
__device__ __forceinline__ float bfhi(uint32_t u){
  union { uint32_t i; float f; } c; c.i = u & 0xffff0000u; return c.f;
}

typedef __attribute__((address_space(1))) const void* gptr_t;
typedef __attribute__((address_space(3))) void* lptr_t;

// r16: dispatch-count reduction 4->3. Evidence (r13: -2.1us from major GEMM change;
// r15: +0.3us from x-pass removal + bank-conflict fix; r14: one-kernel run shows
// ~12us/dispatch fixed overhead): in-kernel work ~20us, boundaries dominate.
// prep kernel eliminated — both GEMMs stage B directly from f32 weights with an
// in-staging transpose (4x4 micro-blocks, f2bf RNE cvt, ds_write_b64 to the SAME
// XOR-swizzled slots the MFMA fragment reads expect; write/read use the identical
// involution chunk=(k>>3)^(n&15)).

// ---------- GEMM: C[M,N] = A[M,256] * B[256,N] + bias(fp32) ----------
// Tile 64 x NT, 4 waves. B staged from f32 [K][N] source (stride N) with
// in-staging transpose. A: AF32 -> staged from f32 x with in-reg cvt + swizzled
// ds_write; AHM -> head-major bf16 via async global_load_lds (linear dest +
// inv-swz source).
#define KDIM 256
#define KHALF 128

template<int OUTF32, int AHM, int NT, int AF32>
__global__ __launch_bounds__(256) void gemm_bt_bias(
    const void* __restrict__ Av,
    const float* __restrict__ Bs,      // f32 [256][N] row-major (w_qkv / w_proj)
    const float* __restrict__ bias,
    void* __restrict__ Cv,
    int N)
{
  constexpr int NF = NT / 32;            // B frags per wave (2 or 4)
  __shared__ __align__(16) uint16_t Al[64 * KHALF];
  __shared__ __align__(16) uint16_t Bl[NT * KHALF];
  const int m0 = blockIdx.x * 64, n0 = blockIdx.y * NT;
  const int t = threadIdx.x;
  const int lane = t & 63;
  const int wave = t >> 6;
  const int wm = (wave & 1) * 32;
  const int wn = (wave >> 1) * (NF * 16);
  const int fr = lane & 15;

  floatx4 acc[2][NF];
  #pragma unroll
  for (int mi = 0; mi < 2; mi++)
    #pragma unroll
    for (int nf = 0; nf < NF; nf++) acc[mi][nf] = (floatx4){0.f,0.f,0.f,0.f};

  constexpr int AGRP = 4;                // 16 wave-groups of 1KB for A, 4 per wave
  constexpr int NMB  = NT / 4;           // B micro-block columns
  constexpr int REPS = (NMB * 32) / 256; // B 4x4 micro-blocks per thread (4 or 2)

  for (int ko = 0; ko < 2; ko++){
    if (ko) __syncthreads();

    // ---- A staging (async path first so loads are in flight during B work) ----
    if (!AF32){
      #pragma unroll
      for (int gg = 0; gg < AGRP; gg++){
        int g = wave + gg * 4;
        int L = g * 64 + lane;
        int row = L >> 4, cs = L & 15;
        int cg = cs ^ (row & 15);
        const uint16_t* ga;
        if (AHM){
          int d0 = ko * KHALF + cg * 8;  // stays within one 32-dim head plane
          ga = (const uint16_t*)Av + (size_t)(d0 >> 5) * (NTOK * 32) + (m0 + row) * 32 + (d0 & 31);
        } else {
          ga = (const uint16_t*)Av + (size_t)(m0 + row) * KDIM + ko * KHALF + cg * 8;
        }
        __builtin_amdgcn_global_load_lds((gptr_t)ga, (lptr_t)(Al + g * 512), 16, 0, 0);
      }
    }

    // ---- B staging: f32 [K][N] -> bf16 transposed into swizzled slots ----
    #pragma unroll
    for (int rep = 0; rep < REPS; rep++){
      int linear = rep * 256 + t;
      int nr = (linear % NMB) * 4;       // n_rel (row in Bl)
      int kr = (linear / NMB) * 4;       // k_rel within this ko half
      const float* src = Bs + (size_t)(ko * KHALF + kr) * N + n0 + nr;
      float4 L0 = *(const float4*)(src);
      float4 L1 = *(const float4*)(src + N);
      float4 L2 = *(const float4*)(src + 2 * N);
      float4 L3 = *(const float4*)(src + 3 * N);
      const int kc = kr >> 3, kof = kr & 7;   // chunk base, 0 or 4 within chunk
      uint2 w2; int row, e;
      row = nr + 0;
      w2.x = (uint32_t)f2bf(L0.x) | ((uint32_t)f2bf(L1.x) << 16);
      w2.y = (uint32_t)f2bf(L2.x) | ((uint32_t)f2bf(L3.x) << 16);
      e = row * KHALF + ((kc ^ (row & 15)) << 3) + kof;
      *(uint2*)(Bl + e) = w2;
      row = nr + 1;
      w2.x = (uint32_t)f2bf(L0.y) | ((uint32_t)f2bf(L1.y) << 16);
      w2.y = (uint32_t)f2bf(L2.y) | ((uint32_t)f2bf(L3.y) << 16);
      e = row * KHALF + ((kc ^ (row & 15)) << 3) + kof;
      *(uint2*)(Bl + e) = w2;
      row = nr + 2;
      w2.x = (uint32_t)f2bf(L0.z) | ((uint32_t)f2bf(L1.z) << 16);
      w2.y = (uint32_t)f2bf(L2.z) | ((uint32_t)f2bf(L3.z) << 16);
      e = row * KHALF + ((kc ^ (row & 15)) << 3) + kof;
      *(uint2*)(Bl + e) = w2;
      row = nr + 3;
      w2.x = (uint32_t)f2bf(L0.w) | ((uint32_t)f2bf(L1.w) << 16);
      w2.y = (uint32_t)f2bf(L2.w) | ((uint32_t)f2bf(L3.w) << 16);
      e = row * KHALF + ((kc ^ (row & 15)) << 3) + kof;
      *(uint2*)(Bl + e) = w2;
    }

    // ---- A staging (blocking f32 path after B so address calc overlaps) ----
    if (AF32){
      #pragma unroll
      for (int gg = 0; gg < AGRP; gg++){
        int g = wave + gg * 4;
        int L = g * 64 + lane;
        int row = L >> 4, cs = L & 15;
        const float* ga = (const float*)Av + (size_t)(m0 + row) * KDIM + ko * KHALF + cs * 8;
        float4 f0 = *(const float4*)ga;
        float4 f1 = *(const float4*)(ga + 4);
        bf16x8 v;
        v[0] = (bf16_t)f0.x; v[1] = (bf16_t)f0.y; v[2] = (bf16_t)f0.z; v[3] = (bf16_t)f0.w;
        v[4] = (bf16_t)f1.x; v[5] = (bf16_t)f1.y; v[6] = (bf16_t)f1.z; v[7] = (bf16_t)f1.w;
        int slot = row * 16 + (cs ^ (row & 15));
        *(bf16x8*)(Al + slot * 8) = v;
      }
    }
    __syncthreads();

    #pragma unroll
    for (int kk = 0; kk < KHALF; kk += 32){
      const int sel = ((((kk >> 3) + (lane >> 4)) ^ fr) << 3);  // swizzled elem offset
      bf16x8 a0 = *(const bf16x8*)(Al + (wm + fr)      * KHALF + sel);
      bf16x8 a1 = *(const bf16x8*)(Al + (wm + 16 + fr) * KHALF + sel);
      bf16x8 bfrag[NF];
      #pragma unroll
      for (int nf = 0; nf < NF; nf++)
        bfrag[nf] = *(const bf16x8*)(Bl + (wn + nf * 16 + fr) * KHALF + sel);
      #pragma unroll
      for (int nf = 0; nf < NF; nf++){
        acc[0][nf] = __builtin_amdgcn_mfma_f32_16x16x32_bf16(a0, bfrag[nf], acc[0][nf], 0, 0, 0);
        acc[1][nf] = __builtin_amdgcn_mfma_f32_16x16x32_bf16(a1, bfrag[nf], acc[1][nf], 0, 0, 0);
      }
    }
  }

  // epilogue: C/D layout col=lane&15, row=(lane>>4)*4+r  [verified m89/m91]
  const int ccol = lane & 15;
  const int crow = (lane >> 4) * 4;
  float bv[NF];
  #pragma unroll
  for (int nf = 0; nf < NF; nf++) bv[nf] = bias[n0 + wn + nf * 16 + ccol];
  #pragma unroll
  for (int mi = 0; mi < 2; mi++){
    #pragma unroll
    for (int r2 = 0; r2 < 4; r2++){
      int r = m0 + wm + mi * 16 + crow + r2;
      #pragma unroll
      for (int nf = 0; nf < NF; nf++){
        int cidx = r * N + n0 + wn + nf * 16 + ccol;
        if (OUTF32) ((float*)Cv)[cidx] = acc[mi][nf][r2] + bv[nf];
        else        ((uint16_t*)Cv)[cidx] = f2bf(acc[mi][nf][r2] + bv[nf]);
      }
    }
  }
}

// ---------- NATTEN attention v5: plane-major LDS, token-XOR bank swizzle ----------
#define WIN 20
#define PPL 3200   // elems per plane: 400 tokens * 8

__global__ __launch_bounds__(256, 3) void natten_kernel(
    const uint16_t* __restrict__ qkv,   // [NTOK][768]
    const float* __restrict__ rpb0,     // [4][13][13]
    const float* __restrict__ rpb1,
    uint16_t* __restrict__ attnH)       // [8][NTOK][32]
{
  __shared__ uint16_t KS[4 * PPL];      // 25600 B
  __shared__ uint16_t VS[4 * PPL];      // 25600 B
  __shared__ float RPB[169];

  const int t = threadIdx.x;
  const int z = blockIdx.x;             // b*8 + h
  const int b = z >> 3, h = z & 7;
  const int j0 = blockIdx.y * 8, i0 = blockIdx.z * 8;
  const int split = h >> 2;
  const int dil = split + 1;
  const float* rpb = (split ? rpb1 : rpb0) + (h & 3) * 169;
  if (t < 169) RPB[t] = rpb[t];

  const int r0 = max(0, i0 - 3 * dil);
  const int c0 = max(0, j0 - 3 * dil);
  const int R  = min(55, i0 + 7 + 3 * dil) - r0 + 1;   // <= 20
  const int C  = min(55, j0 + 7 + 3 * dil) - c0 + 1;   // <= 20

  const int nchunk = R * WIN * 4;       // 16B chunks per array
  for (int ch = t; ch < nchunk; ch += 256){
    int tok = ch >> 2, q = ch & 3;
    int tr = tok / WIN;
    int tc = tok - tr * WIN;
    if (tc < C){                        // skip out-of-window cols (never read)
      const uint16_t* src = qkv + (size_t)((b * HW + r0 + tr) * HW + c0 + tc) * 768
                            + 256 + h * 32 + q * 8;
      int lds = q * PPL + ((tok ^ ((5 * q) & 7)) << 3);
      *(bf16x8*)(KS + lds) = *(const bf16x8*)(src);
      *(bf16x8*)(VS + lds) = *(const bf16x8*)(src + 256);
    }
  }
  __syncthreads();

  const int c  = t & 3;
  const int qi = t >> 2;
  const int j = j0 + (qi & 7);
  const int i = i0 + (qi >> 3);

  const int ri = i % dil, pi = i / dil;
  const int rj = j % dil, pj = j / dil;
  const int Lri = (HW - ri + dil - 1) / dil;
  const int Lrj = (HW - rj + dil - 1) / dil;
  const int psi = min(max(pi - 3, 0), Lri - 7);
  const int psj = min(max(pj - 3, 0), Lrj - 7);
  const int bi0 = psi - pi + 6, bj0 = psj - pj + 6;
  const int ni0 = psi * dil + ri, nj0 = psj * dil + rj;

  const int tok = (b * HW + i) * HW + j;
  const float scale = 0.17677669529663687f;

  const int cpl = c * PPL;              // this lane's plane base
  const int cx  = (5 * c) & 7;          // this lane's token-XOR

  float qv[8];
  {
    uint4 u = *(const uint4*)(qkv + (size_t)tok * 768 + h * 32 + c * 8);
    qv[0] = bflo(u.x) * scale; qv[1] = bfhi(u.x) * scale;
    qv[2] = bflo(u.y) * scale; qv[3] = bfhi(u.y) * scale;
    qv[4] = bflo(u.z) * scale; qv[5] = bfhi(u.z) * scale;
    qv[6] = bflo(u.w) * scale; qv[7] = bfhi(u.w) * scale;
  }

  const int lbase = (ni0 - r0) * WIN + (nj0 - c0);
  float lgl[13];
  lgl[12] = -1e30f;
  #pragma unroll
  for (int ai = 0; ai < 7; ai++){
    int lrow = lbase + ai * dil * WIN;
    int rpi = (bi0 + ai) * 13 + bj0;
    #pragma unroll
    for (int aj = 0; aj < 7; aj++){
      const int a = ai * 7 + aj;
      int tk = lrow + aj * dil;
      uint4 u = *(const uint4*)(KS + cpl + ((tk ^ cx) << 3));
      float d = qv[0] * bflo(u.x) + qv[1] * bfhi(u.x)
              + qv[2] * bflo(u.y) + qv[3] * bfhi(u.y)
              + qv[4] * bflo(u.z) + qv[5] * bfhi(u.z)
              + qv[6] * bflo(u.w) + qv[7] * bfhi(u.w);
      d += __shfl_xor(d, 1);
      d += __shfl_xor(d, 2);
      d += RPB[rpi + aj];
      if ((a & 3) == c) lgl[a >> 2] = d;
    }
  }

  float mx = lgl[0];
  #pragma unroll
  for (int s = 1; s < 13; s++) mx = fmaxf(mx, lgl[s]);
  mx = fmaxf(mx, __shfl_xor(mx, 1));
  mx = fmaxf(mx, __shfl_xor(mx, 2));
  float ssum = 0.f;
  #pragma unroll
  for (int s = 0; s < 13; s++){
    float e = __expf(lgl[s] - mx);
    lgl[s] = e;
    ssum += e;
  }
  ssum += __shfl_xor(ssum, 1);
  ssum += __shfl_xor(ssum, 2);
  float inv = 1.0f / ssum;

  float ov[8];
  #pragma unroll
  for (int d = 0; d < 8; d++) ov[d] = 0.f;

  const int lane4 = t & 60;
  #pragma unroll
  for (int ai = 0; ai < 7; ai++){
    int lrow = lbase + ai * dil * WIN;
    #pragma unroll
    for (int aj = 0; aj < 7; aj++){
      const int a = ai * 7 + aj;
      int tk = lrow + aj * dil;
      uint4 u = *(const uint4*)(VS + cpl + ((tk ^ cx) << 3));
      float w = __shfl(lgl[a >> 2], lane4 | (a & 3)) * inv;
      ov[0] += w * bflo(u.x); ov[1] += w * bfhi(u.x);
      ov[2] += w * bflo(u.y); ov[3] += w * bfhi(u.y);
      ov[4] += w * bflo(u.z); ov[5] += w * bfhi(u.z);
      ov[6] += w * bflo(u.w); ov[7] += w * bfhi(u.w);
    }
  }

  uint4 pk;
  pk.x = (uint32_t)f2bf(ov[0]) | ((uint32_t)f2bf(ov[1]) << 16);
  pk.y = (uint32_t)f2bf(ov[2]) | ((uint32_t)f2bf(ov[3]) << 16);
  pk.z = (uint32_t)f2bf(ov[4]) | ((uint32_t)f2bf(ov[5]) << 16);
  pk.w = (uint32_t)f2bf(ov[6]) | ((uint32_t)f2bf(ov[7]) << 16);
  *(uint4*)(attnH + ((size_t)h * NTOK + tok) * 32 + c * 8) = pk;
}

extern "C" void kernel_launch(void* const* d_in, const int* in_sizes, int n_in,
                              void* d_out, int out_size, void* d_ws, size_t ws_size,
                              hipStream_t stream)
{
  (void)in_sizes; (void)n_in; (void)out_size; (void)ws_size;
  const float* x      = (const float*)d_in[0];
  const float* w_qkv  = (const float*)d_in[1];
  const float* b_qkv  = (const float*)d_in[2];
  const float* w_proj = (const float*)d_in[3];
  const float* b_proj = (const float*)d_in[4];
  const float* rpb0   = (const float*)d_in[5];
  const float* rpb1   = (const float*)d_in[6];
  float* out = (float*)d_out;

  uint16_t* qkv  = (uint16_t*)d_ws;                      // NTOK*768 bf16
  uint16_t* attn = qkv + (size_t)NTOK * 768;             // 8*NTOK*32 (head-major)

  gemm_bt_bias<0, 0, 128, 1><<<dim3(98, 6), 256, 0, stream>>>(x, w_qkv, b_qkv, qkv, 768);
  natten_kernel<<<dim3(16, 7, 7), 256, 0, stream>>>(qkv, rpb0, rpb1, attn);
  gemm_bt_bias<1, 1, 64, 0><<<dim3(98, 4), 256, 0, stream>>>(attn, w_proj, b_proj, out, 256);
}

// Round 5
// 102.725 us; speedup vs baseline: 1.1344x; 1.1344x over previous
//
#include <hip/hip_runtime.h>
#include <stdint.h>

typedef __bf16 bf16_t;
typedef bf16_t bf16x8 __attribute__((ext_vector_type(8)));
typedef bf16_t bf16x2 __attribute__((ext_vector_type(2)));
typedef float floatx4 __attribute__((ext_vector_type(4)));

#define HW 56
#define NTOK 6272   // 2*56*56

__device__ __forceinline__ uint16_t f2bf(float f){
  union { float f; uint32_t i; } c; c.f = f;
  uint32_t r = (c.i + 0x7FFFu + ((c.i >> 16) & 1u)) >> 16;
  return (uint16_t)r;
}
__device__ __forceinline__ float bflo(uint32_t u){
  union { uint32_t i; float f; } c; c.i = u << 16; return c.f;
}
__device__ __forceinline__ float bfhi(uint32_t u){
  union { uint32_t i; float f; } c; c.i = u & 0xffff0000u; return c.f;
}

// packed 2xbf16 dot with f32 accumulate; order-equivalent to unpack+fma
__device__ __forceinline__ float bdot2(uint32_t ka, uint32_t qa, float acc){
#if __has_builtin(__builtin_amdgcn_fdot2_f32_bf16)
  union { uint32_t u; bf16x2 v; } A, B;
  A.u = ka; B.u = qa;
  return __builtin_amdgcn_fdot2_f32_bf16(A.v, B.v, acc, false);
#else
  return acc + bflo(ka) * bflo(qa) + bfhi(ka) * bfhi(qa);
#endif
}

typedef __attribute__((address_space(1))) const void* gptr_t;
typedef __attribute__((address_space(3))) void* lptr_t;

// r17: GEMM/prep reverted to r13 (best measured, 114.7): r16 proved the in-GEMM
// f32 B-transpose costs more than the dispatch it saved (+1.5us) — boundaries
// are ~1-2us, not 12. natten rebuilt (v6): QK is now slot-parallel full-dot —
// thread (q, s) does complete 32-dim dots for keys a=4m+s; kills 98 shfl + 36
// RPB reads per wave (QK DS-pipe 1570->784 cyc/wave), VALU -4x via
// v_dot2_f32_bf16. Key striping a%4==s at index a>>2 is identical to the old
// c-striping, so softmax reduce + entire PV phase are verbatim unchanged.

// ---------- prep: fused x-convert + both weight transposes ----------
__global__ __launch_bounds__(256) void prep_kernel(
    const float* __restrict__ x,      uint16_t* __restrict__ xb,
    const float* __restrict__ w_qkv,  uint16_t* __restrict__ wqkvT,
    const float* __restrict__ w_proj, uint16_t* __restrict__ wprojT)
{
  __shared__ uint16_t tile[64][65];
  const int bx = blockIdx.x;
  const int t = threadIdx.x;
  if (bx < 784){
    int idx = bx * 256 + t;
    const float4* s = (const float4*)x + (size_t)idx * 2;
    float4 a = s[0], b = s[1];
    uint4 pk;
    pk.x = (uint32_t)f2bf(a.x) | ((uint32_t)f2bf(a.y) << 16);
    pk.y = (uint32_t)f2bf(a.z) | ((uint32_t)f2bf(a.w) << 16);
    pk.z = (uint32_t)f2bf(b.x) | ((uint32_t)f2bf(b.y) << 16);
    pk.w = (uint32_t)f2bf(b.z) | ((uint32_t)f2bf(b.w) << 16);
    ((uint4*)xb)[idx] = pk;
    return;
  }
  const float* src; uint16_t* dst; int N, q;
  if (bx < 832){ q = bx - 784; src = w_qkv;  dst = wqkvT;  N = 768; }
  else         { q = bx - 832; src = w_proj; dst = wprojT; N = 256; }
  const int k0 = (q & 3) * 64, n0 = (q >> 2) * 64;   // K=256 always
  for (int idx = t; idx < 64 * 64; idx += 256){
    int r = idx >> 6, c = idx & 63;
    tile[r][c] = f2bf(src[(k0 + r) * N + n0 + c]);
  }
  __syncthreads();
  for (int idx = t; idx < 64 * 64; idx += 256){
    int r = idx >> 6, c = idx & 63;
    dst[(n0 + r) * 256 + k0 + c] = tile[c][r];
  }
}

// ---------- GEMM: C[M,N] = A[M,256](bf16) * Bt[N,256]^T(bf16) + bias(fp32) ----------
// Tile 64 x NT, 4 waves. A and B staged via global_load_lds width=16 (linear
// LDS dest + inverse-XOR-swizzled global source; ds_read uses same involution).
#define KDIM 256
#define KHALF 128

template<int OUTF32, int AHM, int NT>
__global__ __launch_bounds__(256) void gemm_bt_bias(
    const uint16_t* __restrict__ A,
    const uint16_t* __restrict__ Bt,
    const float* __restrict__ bias,
    void* __restrict__ Cv,
    int N)
{
  constexpr int NF = NT / 32;            // B frags per wave (2 or 4)
  __shared__ __align__(16) uint16_t Al[64 * KHALF];
  __shared__ __align__(16) uint16_t Bl[NT * KHALF];
  const int m0 = blockIdx.x * 64, n0 = blockIdx.y * NT;
  const int t = threadIdx.x;
  const int lane = t & 63;
  const int wave = t >> 6;
  const int wm = (wave & 1) * 32;
  const int wn = (wave >> 1) * (NF * 16);
  const int fr = lane & 15;

  floatx4 acc[2][NF];
  #pragma unroll
  for (int mi = 0; mi < 2; mi++)
    #pragma unroll
    for (int nf = 0; nf < NF; nf++) acc[mi][nf] = (floatx4){0.f,0.f,0.f,0.f};

  constexpr int AGRP = 4;                // 16 wave-groups of 1KB for A, 4 per wave
  constexpr int BGRP = NT / 16;          // NT/4 wave-groups for B, /4 waves

  for (int ko = 0; ko < 2; ko++){
    if (ko) __syncthreads();
    #pragma unroll
    for (int gg = 0; gg < AGRP; gg++){
      int g = wave + gg * 4;
      int L = g * 64 + lane;             // 16B-chunk index into Al
      int row = L >> 4, cs = L & 15;
      int cg = cs ^ (row & 15);          // inverse-swizzled global chunk
      const uint16_t* ga;
      if (AHM){
        int d0 = ko * KHALF + cg * 8;    // stays within one 32-dim head plane
        ga = A + (size_t)(d0 >> 5) * (NTOK * 32) + (m0 + row) * 32 + (d0 & 31);
      } else {
        ga = A + (size_t)(m0 + row) * KDIM + ko * KHALF + cg * 8;
      }
      __builtin_amdgcn_global_load_lds((gptr_t)ga, (lptr_t)(Al + g * 512), 16, 0, 0);
    }
    #pragma unroll
    for (int gg = 0; gg < BGRP; gg++){
      int g = wave + gg * 4;
      int L = g * 64 + lane;
      int row = L >> 4, cs = L & 15;
      int cg = cs ^ (row & 15);
      const uint16_t* gb = Bt + (size_t)(n0 + row) * KDIM + ko * KHALF + cg * 8;
      __builtin_amdgcn_global_load_lds((gptr_t)gb, (lptr_t)(Bl + g * 512), 16, 0, 0);
    }
    __syncthreads();
    #pragma unroll
    for (int kk = 0; kk < KHALF; kk += 32){
      const int sel = ((((kk >> 3) + (lane >> 4)) ^ fr) << 3);  // swizzled elem offset
      bf16x8 a0 = *(const bf16x8*)(Al + (wm + fr)      * KHALF + sel);
      bf16x8 a1 = *(const bf16x8*)(Al + (wm + 16 + fr) * KHALF + sel);
      bf16x8 bfrag[NF];
      #pragma unroll
      for (int nf = 0; nf < NF; nf++)
        bfrag[nf] = *(const bf16x8*)(Bl + (wn + nf * 16 + fr) * KHALF + sel);
      #pragma unroll
      for (int nf = 0; nf < NF; nf++){
        acc[0][nf] = __builtin_amdgcn_mfma_f32_16x16x32_bf16(a0, bfrag[nf], acc[0][nf], 0, 0, 0);
        acc[1][nf] = __builtin_amdgcn_mfma_f32_16x16x32_bf16(a1, bfrag[nf], acc[1][nf], 0, 0, 0);
      }
    }
  }

  // epilogue: C/D layout col=lane&15, row=(lane>>4)*4+r  [verified m89/m91]
  const int ccol = lane & 15;
  const int crow = (lane >> 4) * 4;
  float bv[NF];
  #pragma unroll
  for (int nf = 0; nf < NF; nf++) bv[nf] = bias[n0 + wn + nf * 16 + ccol];
  #pragma unroll
  for (int mi = 0; mi < 2; mi++){
    #pragma unroll
    for (int r2 = 0; r2 < 4; r2++){
      int r = m0 + wm + mi * 16 + crow + r2;
      #pragma unroll
      for (int nf = 0; nf < NF; nf++){
        int cidx = r * N + n0 + wn + nf * 16 + ccol;
        if (OUTF32) ((float*)Cv)[cidx] = acc[mi][nf][r2] + bv[nf];
        else        ((uint16_t*)Cv)[cidx] = f2bf(acc[mi][nf][r2] + bv[nf]);
      }
    }
  }
}

// ---------- NATTEN attention v6: slot-parallel full-dot QK ----------
// QK: thread (query q, slot s=t&3) computes FULL 32-dim dots for keys a=4m+s
// (m=0..12): 4x ds_read_b128 per key, ZERO shfls, 13 RPB reads. Key striping
// a%4==s at index a>>2 is identical to the old c-striping -> softmax reduce
// and PV phase unchanged. K layout: row-major [400][32] with double-XOR chunk
// swizzle (cc ^ (tok&3) ^ ((tok>>2)&3)) on write AND read -> <=2-way banks for
// the 64-distinct-token read pattern (dil=1 and dil=2). V stays plane-major.
#define WIN 20
#define PPL 3200   // V plane stride: 400 tokens * 8

__global__ __launch_bounds__(256, 3) void natten_kernel(
    const uint16_t* __restrict__ qkv,   // [NTOK][768]
    const float* __restrict__ rpb0,     // [4][13][13]
    const float* __restrict__ rpb1,
    uint16_t* __restrict__ attnH)       // [8][NTOK][32]
{
  __shared__ uint16_t KS[400 * 32];     // 25600 B, row-major per token
  __shared__ uint16_t VS[4 * PPL];      // 25600 B, plane-major
  __shared__ float RPB[169];

  const int t = threadIdx.x;
  const int z = blockIdx.x;             // b*8 + h
  const int b = z >> 3, h = z & 7;
  const int j0 = blockIdx.y * 8, i0 = blockIdx.z * 8;
  const int split = h >> 2;
  const int dil = split + 1;
  const float* rpb = (split ? rpb1 : rpb0) + (h & 3) * 169;
  if (t < 169) RPB[t] = rpb[t];

  const int r0 = max(0, i0 - 3 * dil);
  const int c0 = max(0, j0 - 3 * dil);
  const int R  = min(55, i0 + 7 + 3 * dil) - r0 + 1;   // <= 20
  const int C  = min(55, j0 + 7 + 3 * dil) - c0 + 1;   // <= 20

  const int nchunk = R * WIN * 4;       // 16B chunks per array
  for (int ch = t; ch < nchunk; ch += 256){
    int tok = ch >> 2, q = ch & 3;
    int tr = tok / WIN;
    int tc = tok - tr * WIN;
    if (tc < C){                        // skip out-of-window cols (never read)
      const uint16_t* src = qkv + (size_t)((b * HW + r0 + tr) * HW + c0 + tc) * 768
                            + 256 + h * 32 + q * 8;
      int kl = tok * 32 + ((q ^ (tok & 3) ^ ((tok >> 2) & 3)) << 3);
      *(bf16x8*)(KS + kl) = *(const bf16x8*)(src);
      int vl = q * PPL + ((tok ^ ((5 * q) & 7)) << 3);
      *(bf16x8*)(VS + vl) = *(const bf16x8*)(src + 256);
    }
  }
  __syncthreads();

  const int c  = t & 3;                 // QK: key slot; PV: dim slot
  const int qi = t >> 2;
  const int j = j0 + (qi & 7);
  const int i = i0 + (qi >> 3);

  const int ri = i % dil, pi = i / dil;
  const int rj = j % dil, pj = j / dil;
  const int Lri = (HW - ri + dil - 1) / dil;
  const int Lrj = (HW - rj + dil - 1) / dil;
  const int psi = min(max(pi - 3, 0), Lri - 7);
  const int psj = min(max(pj - 3, 0), Lrj - 7);
  const int bi0 = psi - pi + 6, bj0 = psj - pj + 6;
  const int ni0 = psi * dil + ri, nj0 = psj * dil + rj;

  const int tok = (b * HW + i) * HW + j;
  const float scale = 0.17677669529663687f;

  // full 32-dim Q row, packed 2xbf16 per reg (scale applied post-dot)
  uint32_t qp[16];
  {
    const uint16_t* qsrc = qkv + (size_t)tok * 768 + h * 32;
    uint4 u0 = *(const uint4*)(qsrc);
    uint4 u1 = *(const uint4*)(qsrc + 8);
    uint4 u2 = *(const uint4*)(qsrc + 16);
    uint4 u3 = *(const uint4*)(qsrc + 24);
    qp[0]  = u0.x; qp[1]  = u0.y; qp[2]  = u0.z; qp[3]  = u0.w;
    qp[4]  = u1.x; qp[5]  = u1.y; qp[6]  = u1.z; qp[7]  = u1.w;
    qp[8]  = u2.x; qp[9]  = u2.y; qp[10] = u2.z; qp[11] = u2.w;
    qp[12] = u3.x; qp[13] = u3.y; qp[14] = u3.z; qp[15] = u3.w;
  }

  const int lbase = (ni0 - r0) * WIN + (nj0 - c0);

  float lgl[13];
  #pragma unroll
  for (int m = 0; m < 13; m++){
    int a = 4 * m + c;                  // this slot's key index
    const bool valid = (a <= 48);
    if (!valid) a = 48;                 // clamp: safe read, logit forced -inf
    int ai = a / 7;
    int aj = a - ai * 7;
    int tk = lbase + (ai * WIN + aj) * dil;
    const int tswz = ((tk & 3) ^ ((tk >> 2) & 3));
    float dacc = 0.f;
    #pragma unroll
    for (int cc = 0; cc < 4; cc++){
      uint4 u = *(const uint4*)(KS + tk * 32 + ((cc ^ tswz) << 3));
      dacc = bdot2(u.x, qp[cc * 4 + 0], dacc);
      dacc = bdot2(u.y, qp[cc * 4 + 1], dacc);
      dacc = bdot2(u.z, qp[cc * 4 + 2], dacc);
      dacc = bdot2(u.w, qp[cc * 4 + 3], dacc);
    }
    float d = dacc * scale + RPB[(bi0 + ai) * 13 + (bj0 + aj)];
    lgl[m] = valid ? d : -1e30f;
  }

  float mx = lgl[0];
  #pragma unroll
  for (int s = 1; s < 13; s++) mx = fmaxf(mx, lgl[s]);
  mx = fmaxf(mx, __shfl_xor(mx, 1));
  mx = fmaxf(mx, __shfl_xor(mx, 2));
  float ssum = 0.f;
  #pragma unroll
  for (int s = 0; s < 13; s++){
    float e = __expf(lgl[s] - mx);
    lgl[s] = e;
    ssum += e;
  }
  ssum += __shfl_xor(ssum, 1);
  ssum += __shfl_xor(ssum, 2);
  float inv = 1.0f / ssum;

  float ov[8];
  #pragma unroll
  for (int d = 0; d < 8; d++) ov[d] = 0.f;

  const int cpl = c * PPL;              // PV: this lane's V plane base
  const int cx  = (5 * c) & 7;          // PV: this lane's token-XOR
  const int lane4 = t & 60;
  #pragma unroll
  for (int ai = 0; ai < 7; ai++){
    int lrow = lbase + ai * dil * WIN;
    #pragma unroll
    for (int aj = 0; aj < 7; aj++){
      const int a = ai * 7 + aj;
      int tk = lrow + aj * dil;
      uint4 u = *(const uint4*)(VS + cpl + ((tk ^ cx) << 3));
      float w = __shfl(lgl[a >> 2], lane4 | (a & 3)) * inv;
      ov[0] += w * bflo(u.x); ov[1] += w * bfhi(u.x);
      ov[2] += w * bflo(u.y); ov[3] += w * bfhi(u.y);
      ov[4] += w * bflo(u.z); ov[5] += w * bfhi(u.z);
      ov[6] += w * bflo(u.w); ov[7] += w * bfhi(u.w);
    }
  }

  uint4 pk;
  pk.x = (uint32_t)f2bf(ov[0]) | ((uint32_t)f2bf(ov[1]) << 16);
  pk.y = (uint32_t)f2bf(ov[2]) | ((uint32_t)f2bf(ov[3]) << 16);
  pk.z = (uint32_t)f2bf(ov[4]) | ((uint32_t)f2bf(ov[5]) << 16);
  pk.w = (uint32_t)f2bf(ov[6]) | ((uint32_t)f2bf(ov[7]) << 16);
  *(uint4*)(attnH + ((size_t)h * NTOK + tok) * 32 + c * 8) = pk;
}

extern "C" void kernel_launch(void* const* d_in, const int* in_sizes, int n_in,
                              void* d_out, int out_size, void* d_ws, size_t ws_size,
                              hipStream_t stream)
{
  (void)in_sizes; (void)n_in; (void)out_size; (void)ws_size;
  const float* x      = (const float*)d_in[0];
  const float* w_qkv  = (const float*)d_in[1];
  const float* b_qkv  = (const float*)d_in[2];
  const float* w_proj = (const float*)d_in[3];
  const float* b_proj = (const float*)d_in[4];
  const float* rpb0   = (const float*)d_in[5];
  const float* rpb1   = (const float*)d_in[6];
  float* out = (float*)d_out;

  uint16_t* wqkvT  = (uint16_t*)d_ws;                    // 768*256
  uint16_t* wprojT = wqkvT + 768 * 256;                  // 256*256
  uint16_t* xb     = wprojT + 256 * 256;                 // NTOK*256
  uint16_t* qkv    = xb + (size_t)NTOK * 256;            // NTOK*768
  uint16_t* attn   = qkv + (size_t)NTOK * 768;           // 8*NTOK*32 (head-major)

  prep_kernel<<<dim3(848), 256, 0, stream>>>(x, xb, w_qkv, wqkvT, w_proj, wprojT);
  gemm_bt_bias<0, 0, 128><<<dim3(98, 6), 256, 0, stream>>>(xb, wqkvT, b_qkv, qkv, 768);
  natten_kernel<<<dim3(16, 7, 7), 256, 0, stream>>>(qkv, rpb0, rpb1, attn);
  gemm_bt_bias<1, 1, 64><<<dim3(98, 4), 256, 0, stream>>>(attn, wprojT, b_proj, out, 256);
}